// Round 1
// baseline (445.639 us; speedup 1.0000x reference)
//
#include <hip/hip_runtime.h>
#include <hip/hip_bf16.h>

#define NV 16384
#define DD 128

typedef __attribute__((ext_vector_type(8))) short bf16x8;
typedef __attribute__((ext_vector_type(4))) float f32x4;
typedef __attribute__((ext_vector_type(8))) unsigned short ushort8v;

__device__ __forceinline__ unsigned short f2bf(float x) {
  unsigned u = __builtin_bit_cast(unsigned, x);
  u = (u + 0x7FFFu + ((u >> 16) & 1u)) >> 16;   // round-to-nearest-even
  return (unsigned short)u;
}

__device__ __forceinline__ bf16x8 cvt8(f32x4 a, f32x4 b) {
  bf16x8 r;
#pragma unroll
  for (int i = 0; i < 4; ++i) {
    r[i]     = (short)f2bf(a[i]);
    r[i + 4] = (short)f2bf(b[i]);
  }
  return r;
}

// ---------------------------------------------------------------------------
// Kernel 1: rwh = h * reg_param[region_index];  ws_ra = rwh@W + bias (f32);
//           tT[j][k] = (rwh@LW)[k][j] as bf16   (transposed for MFMA B frags)
// ---------------------------------------------------------------------------
__global__ __launch_bounds__(128) void k_small(
    const float* __restrict__ h, const int* __restrict__ ridx,
    const float* __restrict__ W, const float* __restrict__ LW,
    const float* __restrict__ RP, const float* __restrict__ bias,
    float* __restrict__ ws_ra, unsigned short* __restrict__ tT)
{
  __shared__ float rwhs[8][DD];
  const int v0 = blockIdx.x * 8;
  const int j  = threadIdx.x;
#pragma unroll
  for (int v = 0; v < 8; ++v) {
    const int i = v0 + v;
    const int r = ridx[i] & 63;               // N_REGIONS=64, mask keeps in-range
    rwhs[v][j] = h[(size_t)i * DD + j] * RP[r * DD + j];
  }
  __syncthreads();

  float ra[8], tt[8];
  const float bj = bias[j];
#pragma unroll
  for (int v = 0; v < 8; ++v) { ra[v] = bj; tt[v] = 0.f; }

  for (int d = 0; d < DD; d += 4) {
    f32x4 rv[8];
#pragma unroll
    for (int v = 0; v < 8; ++v) rv[v] = *(const f32x4*)&rwhs[v][d];
#pragma unroll
    for (int dd = 0; dd < 4; ++dd) {
      const float w_  = W[(d + dd) * DD + j];
      const float lw_ = LW[(d + dd) * DD + j];
#pragma unroll
      for (int v = 0; v < 8; ++v) {
        ra[v] = fmaf(rv[v][dd], w_,  ra[v]);
        tt[v] = fmaf(rv[v][dd], lw_, tt[v]);
      }
    }
  }
#pragma unroll
  for (int v = 0; v < 8; ++v) ws_ra[(size_t)(v0 + v) * DD + j] = ra[v];
  ushort8v pk;
#pragma unroll
  for (int v = 0; v < 8; ++v) pk[v] = f2bf(tt[v]);
  *(ushort8v*)&tT[(size_t)j * NV + v0] = pk;
}

// ---------------------------------------------------------------------------
// Kernel 2: out = adj @ t + ws_ra.   BM=64 (4 waves x 16 rows), BK=64.
// A: global f32 -> reg -> bf16 (streamed once, nontemporal).
// B: tT tile staged to LDS via global_load_lds (16B), XOR-swizzled source,
//    double-buffered; ds_read_b128 fragments conflict-free.
// ---------------------------------------------------------------------------
__global__ __launch_bounds__(256) void k_big(
    const float* __restrict__ adj, const unsigned short* __restrict__ tT,
    const float* __restrict__ ws_ra, float* __restrict__ out)
{
  __shared__ unsigned short Bs[2][128 * 64];   // 2 x 16 KB
  const int tid  = threadIdx.x;
  const int w    = tid >> 6;
  const int lane = tid & 63;
  const int g    = lane >> 4;       // k-chunk group 0..3
  const int l15  = lane & 15;
  const int r0   = blockIdx.x * 64;
  const int arow = r0 + w * 16 + l15;
  const float* abase = adj + (size_t)arow * NV + g * 8;

  f32x4 acc[8];
#pragma unroll
  for (int f = 0; f < 8; ++f) acc[f] = (f32x4){0.f, 0.f, 0.f, 0.f};

  auto STAGE = [&](int buf, int t) {
    const int k0 = t * 64;
#pragma unroll
    for (int i = 0; i < 4; ++i) {
      const int unit = i * 4 + w;            // 0..15, wave-uniform
      const int idx  = unit * 64 + lane;     // 0..1023
      const int j    = idx >> 3;             // tT row 0..127
      const int c    = idx & 7;              // 16B chunk slot in LDS row
      const int cg   = c ^ (j & 7);          // inverse-swizzled global chunk
      const unsigned short* src = tT + (size_t)j * NV + k0 + cg * 8;
      unsigned short* dst = &Bs[buf][unit * 512];   // wave-uniform base
      __builtin_amdgcn_global_load_lds(
          (const __attribute__((address_space(1))) unsigned int*)src,
          (__attribute__((address_space(3))) unsigned int*)dst,
          16, 0, 0);
    }
  };

  auto LOADA = [&](int t, f32x4& x0, f32x4& x1, f32x4& x2, f32x4& x3) {
    const f32x4* p = (const f32x4*)(abase + (size_t)t * 64);
    x0 = __builtin_nontemporal_load(p);
    x1 = __builtin_nontemporal_load(p + 1);
    const f32x4* q = (const f32x4*)(abase + (size_t)t * 64 + 32);
    x2 = __builtin_nontemporal_load(q);
    x3 = __builtin_nontemporal_load(q + 1);
  };

  STAGE(0, 0);
  f32x4 c0, c1, c2, c3;
  LOADA(0, c0, c1, c2, c3);
  __syncthreads();

  for (int t = 0; t < 256; ++t) {
    const int buf = t & 1;
    f32x4 n0, n1, n2, n3;
    if (t + 1 < 256) {
      STAGE(buf ^ 1, t + 1);        // prefetch next B tile (other buffer)
      LOADA(t + 1, n0, n1, n2, n3); // prefetch next A regs
    } else {
      n0 = c0; n1 = c1; n2 = c2; n3 = c3;
    }
    const bf16x8 a0 = cvt8(c0, c1);           // k0..k0+31
    const bf16x8 a1 = cvt8(c2, c3);           // k0+32..k0+63
#pragma unroll
    for (int f = 0; f < 8; ++f) {
      const int jrow = f * 16 + l15;
      const bf16x8 b0 = *(const bf16x8*)&Bs[buf][jrow * 64 + ((g ^ (lane & 7)) * 8)];
      acc[f] = __builtin_amdgcn_mfma_f32_16x16x32_bf16(a0, b0, acc[f], 0, 0, 0);
      const bf16x8 b1 = *(const bf16x8*)&Bs[buf][jrow * 64 + (((4 + g) ^ (lane & 7)) * 8)];
      acc[f] = __builtin_amdgcn_mfma_f32_16x16x32_bf16(a1, b1, acc[f], 0, 0, 0);
    }
    __syncthreads();
    c0 = n0; c1 = n1; c2 = n2; c3 = n3;
  }

  // epilogue: out = rb + (ra + bias).  C/D map: col=lane&15, row=(lane>>4)*4+q
  const float* rabase = ws_ra + (size_t)(r0 + w * 16) * DD;
  float*       obase  = out   + (size_t)(r0 + w * 16) * DD;
#pragma unroll
  for (int f = 0; f < 8; ++f) {
    const int col = f * 16 + l15;
#pragma unroll
    for (int q = 0; q < 4; ++q) {
      const int row = g * 4 + q;
      obase[row * DD + col] = acc[f][q] + rabase[row * DD + col];
    }
  }
}

extern "C" void kernel_launch(void* const* d_in, const int* in_sizes, int n_in,
                              void* d_out, int out_size, void* d_ws, size_t ws_size,
                              hipStream_t stream) {
  const float* h    = (const float*)d_in[0];
  const float* adj  = (const float*)d_in[1];
  const int*   ridx = (const int*)d_in[2];
  const float* W    = (const float*)d_in[3];
  const float* LW   = (const float*)d_in[4];
  const float* RP   = (const float*)d_in[5];
  const float* bias = (const float*)d_in[6];
  float* out = (float*)d_out;

  float*          ws_ra = (float*)d_ws;                                  // 8 MB
  unsigned short* tT    = (unsigned short*)((char*)d_ws + (size_t)NV * DD * 4); // 4 MB

  hipLaunchKernelGGL(k_small, dim3(NV / 8), dim3(128), 0, stream,
                     h, ridx, W, LW, RP, bias, ws_ra, tT);
  hipLaunchKernelGGL(k_big, dim3(NV / 64), dim3(256), 0, stream,
                     adj, tT, ws_ra, out);
}

// Round 2
// 367.394 us; speedup vs baseline: 1.2130x; 1.2130x over previous
//
#include <hip/hip_runtime.h>
#include <hip/hip_bf16.h>

#define NV 16384
#define DD 128

typedef __attribute__((ext_vector_type(8))) short bf16x8;
typedef __attribute__((ext_vector_type(4))) float f32x4;
typedef __attribute__((ext_vector_type(8))) unsigned short ushort8v;

__device__ __forceinline__ unsigned short f2bf(float x) {
  unsigned u = __builtin_bit_cast(unsigned, x);
  u = (u + 0x7FFFu + ((u >> 16) & 1u)) >> 16;   // round-to-nearest-even
  return (unsigned short)u;
}

__device__ __forceinline__ bf16x8 cvt8(f32x4 a, f32x4 b) {
  bf16x8 r;
#pragma unroll
  for (int i = 0; i < 4; ++i) {
    r[i]     = (short)f2bf(a[i]);
    r[i + 4] = (short)f2bf(b[i]);
  }
  return r;
}

// ---------------------------------------------------------------------------
// Kernel 1: rwh = h * reg_param[region_index];  ws_ra = rwh@W + bias (f32);
//           tT[j][k] = (rwh@LW)[k][j] as bf16   (transposed for MFMA B frags)
// ---------------------------------------------------------------------------
__global__ __launch_bounds__(128) void k_small(
    const float* __restrict__ h, const int* __restrict__ ridx,
    const float* __restrict__ W, const float* __restrict__ LW,
    const float* __restrict__ RP, const float* __restrict__ bias,
    float* __restrict__ ws_ra, unsigned short* __restrict__ tT)
{
  __shared__ float rwhs[8][DD];
  const int v0 = blockIdx.x * 8;
  const int j  = threadIdx.x;
#pragma unroll
  for (int v = 0; v < 8; ++v) {
    const int i = v0 + v;
    const int r = ridx[i] & 63;               // N_REGIONS=64, mask keeps in-range
    rwhs[v][j] = h[(size_t)i * DD + j] * RP[r * DD + j];
  }
  __syncthreads();

  float ra[8], tt[8];
  const float bj = bias[j];
#pragma unroll
  for (int v = 0; v < 8; ++v) { ra[v] = bj; tt[v] = 0.f; }

  for (int d = 0; d < DD; d += 4) {
    f32x4 rv[8];
#pragma unroll
    for (int v = 0; v < 8; ++v) rv[v] = *(const f32x4*)&rwhs[v][d];
#pragma unroll
    for (int dd = 0; dd < 4; ++dd) {
      const float w_  = W[(d + dd) * DD + j];
      const float lw_ = LW[(d + dd) * DD + j];
#pragma unroll
      for (int v = 0; v < 8; ++v) {
        ra[v] = fmaf(rv[v][dd], w_,  ra[v]);
        tt[v] = fmaf(rv[v][dd], lw_, tt[v]);
      }
    }
  }
#pragma unroll
  for (int v = 0; v < 8; ++v) ws_ra[(size_t)(v0 + v) * DD + j] = ra[v];
  ushort8v pk;
#pragma unroll
  for (int v = 0; v < 8; ++v) pk[v] = f2bf(tt[v]);
  *(ushort8v*)&tT[(size_t)j * NV + v0] = pk;
}

// ---------------------------------------------------------------------------
// Kernel 2: out = adj @ t + ws_ra.   BM=64 (4 waves x 16 rows), BK=64.
// A: global f32 -> reg -> bf16 (streamed once, nontemporal).
// B: tT tile staged to LDS via global_load_lds (16B), XOR-swizzled source,
//    double-buffered; ds_read_b128 fragments 2-way (free).
// Sync: T3/T4 counted vmcnt(8) — prev iter's 8 loads awaited, this iter's 8
// stay in flight across the barrier. vmcnt(0) only on the final iteration.
// ---------------------------------------------------------------------------
__global__ __launch_bounds__(256) void k_big(
    const float* __restrict__ adj, const unsigned short* __restrict__ tT,
    const float* __restrict__ ws_ra, float* __restrict__ out)
{
  __shared__ unsigned short Bs[2][128 * 64];   // 2 x 16 KB
  const int tid  = threadIdx.x;
  const int w    = tid >> 6;
  const int lane = tid & 63;
  const int g    = lane >> 4;       // k-chunk group 0..3
  const int l15  = lane & 15;
  const int r0   = blockIdx.x * 64;
  const int arow = r0 + w * 16 + l15;
  const float* abase = adj + (size_t)arow * NV + g * 8;

  f32x4 acc[8];
#pragma unroll
  for (int f = 0; f < 8; ++f) acc[f] = (f32x4){0.f, 0.f, 0.f, 0.f};

  auto STAGE = [&](int buf, int t) {
    const int k0 = t * 64;
#pragma unroll
    for (int i = 0; i < 4; ++i) {
      const int unit = i * 4 + w;            // 0..15, wave-uniform
      const int idx  = unit * 64 + lane;     // 0..1023
      const int j    = idx >> 3;             // tT row 0..127
      const int c    = idx & 7;              // 16B chunk slot in LDS row
      const int cg   = c ^ (j & 7);          // inverse-swizzled global chunk
      const unsigned short* src = tT + (size_t)j * NV + k0 + cg * 8;
      unsigned short* dst = &Bs[buf][unit * 512];   // wave-uniform base
      __builtin_amdgcn_global_load_lds(
          (const __attribute__((address_space(1))) unsigned int*)src,
          (__attribute__((address_space(3))) unsigned int*)dst,
          16, 0, 0);
    }
  };

  auto LOADA = [&](int t, f32x4& x0, f32x4& x1, f32x4& x2, f32x4& x3) {
    const f32x4* p = (const f32x4*)(abase + (size_t)t * 64);
    x0 = __builtin_nontemporal_load(p);
    x1 = __builtin_nontemporal_load(p + 1);
    const f32x4* q = (const f32x4*)(abase + (size_t)t * 64 + 32);
    x2 = __builtin_nontemporal_load(q);
    x3 = __builtin_nontemporal_load(q + 1);
  };

  // prologue: issue tile 0 (8 VMEM ops); iter 0's vmcnt(8) waits for them
  STAGE(0, 0);
  f32x4 c0, c1, c2, c3;
  LOADA(0, c0, c1, c2, c3);

  for (int t = 0; t < 256; ++t) {
    const int buf = t & 1;
    f32x4 n0, n1, n2, n3;
    if (t + 1 < 256) {
      STAGE(buf ^ 1, t + 1);        // 4 global_load_lds, stay in flight
      LOADA(t + 1, n0, n1, n2, n3); // 4 reg loads, stay in flight
      asm volatile("s_waitcnt vmcnt(8)" ::: "memory");  // prev iter's 8 done
    } else {
      n0 = c0; n1 = c1; n2 = c2; n3 = c3;
      asm volatile("s_waitcnt vmcnt(0)" ::: "memory");  // final tile: drain
    }
    __builtin_amdgcn_s_barrier();   // B(t) visible to all waves

    const bf16x8 a0 = cvt8(c0, c1);           // k0..k0+31
    const bf16x8 a1 = cvt8(c2, c3);           // k0+32..k0+63
#pragma unroll
    for (int f = 0; f < 8; ++f) {
      const int jrow = f * 16 + l15;
      const bf16x8 b0 = *(const bf16x8*)&Bs[buf][jrow * 64 + ((g ^ (lane & 7)) * 8)];
      acc[f] = __builtin_amdgcn_mfma_f32_16x16x32_bf16(a0, b0, acc[f], 0, 0, 0);
      const bf16x8 b1 = *(const bf16x8*)&Bs[buf][jrow * 64 + (((4 + g) ^ (lane & 7)) * 8)];
      acc[f] = __builtin_amdgcn_mfma_f32_16x16x32_bf16(a1, b1, acc[f], 0, 0, 0);
    }
    __builtin_amdgcn_s_barrier();   // all waves done reading buf before rewrite
    c0 = n0; c1 = n1; c2 = n2; c3 = n3;
  }

  // epilogue: out = rb + (ra + bias).  C/D map: col=lane&15, row=(lane>>4)*4+q
  const float* rabase = ws_ra + (size_t)(r0 + w * 16) * DD;
  float*       obase  = out   + (size_t)(r0 + w * 16) * DD;
#pragma unroll
  for (int f = 0; f < 8; ++f) {
    const int col = f * 16 + l15;
#pragma unroll
    for (int q = 0; q < 4; ++q) {
      const int row = g * 4 + q;
      obase[row * DD + col] = acc[f][q] + rabase[row * DD + col];
    }
  }
}

extern "C" void kernel_launch(void* const* d_in, const int* in_sizes, int n_in,
                              void* d_out, int out_size, void* d_ws, size_t ws_size,
                              hipStream_t stream) {
  const float* h    = (const float*)d_in[0];
  const float* adj  = (const float*)d_in[1];
  const int*   ridx = (const int*)d_in[2];
  const float* W    = (const float*)d_in[3];
  const float* LW   = (const float*)d_in[4];
  const float* RP   = (const float*)d_in[5];
  const float* bias = (const float*)d_in[6];
  float* out = (float*)d_out;

  float*          ws_ra = (float*)d_ws;                                  // 8 MB
  unsigned short* tT    = (unsigned short*)((char*)d_ws + (size_t)NV * DD * 4); // 4 MB

  hipLaunchKernelGGL(k_small, dim3(NV / 8), dim3(128), 0, stream,
                     h, ridx, W, LW, RP, bias, ws_ra, tT);
  hipLaunchKernelGGL(k_big, dim3(NV / 64), dim3(256), 0, stream,
                     adj, tT, ws_ra, out);
}

// Round 3
// 346.768 us; speedup vs baseline: 1.2851x; 1.0595x over previous
//
#include <hip/hip_runtime.h>
#include <hip/hip_bf16.h>

#define NV 16384
#define DD 128

typedef __attribute__((ext_vector_type(4))) float f32x4;
typedef __attribute__((ext_vector_type(2))) int i32x2;
typedef long long i64;

#define ASCALE 16384.0f
#define INV_ASCALE (1.0f / 16384.0f)

__device__ __forceinline__ i64 pk8(f32x4 a, f32x4 b, float s) {
  int lo = 0, hi = 0;
  lo = __builtin_amdgcn_cvt_pk_fp8_f32(a[0] * s, a[1] * s, lo, false);
  lo = __builtin_amdgcn_cvt_pk_fp8_f32(a[2] * s, a[3] * s, lo, true);
  hi = __builtin_amdgcn_cvt_pk_fp8_f32(b[0] * s, b[1] * s, hi, false);
  hi = __builtin_amdgcn_cvt_pk_fp8_f32(b[2] * s, b[3] * s, hi, true);
  i32x2 r; r[0] = lo; r[1] = hi;
  return __builtin_bit_cast(i64, r);
}

// ---------------------------------------------------------------------------
// Kernel 1: rwh = h * reg_param[region_index];  ws_ra = rwh@W + bias (f32);
//           tT8 = (rwh@LW) as fp8 e4m3, k-chunk-major blocked layout:
//           [t=NV/64][g8=8][j=128] x 8 bytes  (one 8-k chunk per thread write)
// ---------------------------------------------------------------------------
__global__ __launch_bounds__(128) void k_small(
    const float* __restrict__ h, const int* __restrict__ ridx,
    const float* __restrict__ W, const float* __restrict__ LW,
    const float* __restrict__ RP, const float* __restrict__ bias,
    float* __restrict__ ws_ra, i32x2* __restrict__ tT8)
{
  __shared__ float rwhs[8][DD];
  const int v0 = blockIdx.x * 8;
  const int j  = threadIdx.x;
#pragma unroll
  for (int v = 0; v < 8; ++v) {
    const int i = v0 + v;
    const int r = ridx[i] & 63;               // N_REGIONS=64, mask keeps in-range
    rwhs[v][j] = h[(size_t)i * DD + j] * RP[r * DD + j];
  }
  __syncthreads();

  float ra[8], tt[8];
  const float bj = bias[j];
#pragma unroll
  for (int v = 0; v < 8; ++v) { ra[v] = bj; tt[v] = 0.f; }

  for (int d = 0; d < DD; d += 4) {
    f32x4 rv[8];
#pragma unroll
    for (int v = 0; v < 8; ++v) rv[v] = *(const f32x4*)&rwhs[v][d];
#pragma unroll
    for (int dd = 0; dd < 4; ++dd) {
      const float w_  = W[(d + dd) * DD + j];
      const float lw_ = LW[(d + dd) * DD + j];
#pragma unroll
      for (int v = 0; v < 8; ++v) {
        ra[v] = fmaf(rv[v][dd], w_,  ra[v]);
        tt[v] = fmaf(rv[v][dd], lw_, tt[v]);
      }
    }
  }
#pragma unroll
  for (int v = 0; v < 8; ++v) ws_ra[(size_t)(v0 + v) * DD + j] = ra[v];

  int lo = 0, hi = 0;                          // 8 k-values -> 8 fp8 bytes
  lo = __builtin_amdgcn_cvt_pk_fp8_f32(tt[0], tt[1], lo, false);
  lo = __builtin_amdgcn_cvt_pk_fp8_f32(tt[2], tt[3], lo, true);
  hi = __builtin_amdgcn_cvt_pk_fp8_f32(tt[4], tt[5], hi, false);
  hi = __builtin_amdgcn_cvt_pk_fp8_f32(tt[6], tt[7], hi, true);
  i32x2 val; val[0] = lo; val[1] = hi;
  tT8[(v0 >> 6) * 1024 + ((v0 >> 3) & 7) * 128 + j] = val;
}

// ---------------------------------------------------------------------------
// Kernel 2: out = adj @ t + ws_ra.   BM=64 (4 waves x 16 rows), BK=64, fp8.
// A: adj f32 -> reg -> fp8 (x2^14, streamed once, nontemporal).
// B: fp8 tile (8KB) staged linearly via global_load_lds; k-chunk-major layout
//    makes b64 fragment reads bank-conflict-free with zero swizzle.
// Sync: counted vmcnt(6) — prev iter's 6 VMEM ops awaited, this iter's 6
// stay in flight across the barrier. vmcnt(0) only on the final iteration.
// ---------------------------------------------------------------------------
__global__ __launch_bounds__(256) void k_big(
    const float* __restrict__ adj, const unsigned char* __restrict__ tTb,
    const float* __restrict__ ws_ra, float* __restrict__ out)
{
  __shared__ unsigned char Bs[2][8192] __attribute__((aligned(16)));
  const int tid  = threadIdx.x;
  const int w    = tid >> 6;
  const int lane = tid & 63;
  const int g    = lane >> 4;       // k-chunk group 0..3
  const int l15  = lane & 15;
  const int r0   = blockIdx.x * 64;
  const int arow = r0 + w * 16 + l15;
  const float* abase = adj + (size_t)arow * NV + g * 8;

  f32x4 acc[8];
#pragma unroll
  for (int f = 0; f < 8; ++f) acc[f] = (f32x4){0.f, 0.f, 0.f, 0.f};

  auto STAGE = [&](int buf, int t) {
#pragma unroll
    for (int i = 0; i < 2; ++i) {
      const int unit = i * 4 + w;                      // 0..7, wave-uniform
      const unsigned char* src = tTb + (size_t)t * 8192 + unit * 1024 + lane * 16;
      unsigned char* dst = &Bs[buf][unit * 1024];      // wave-uniform base
      __builtin_amdgcn_global_load_lds(
          (const __attribute__((address_space(1))) unsigned int*)src,
          (__attribute__((address_space(3))) unsigned int*)dst,
          16, 0, 0);
    }
  };

  auto LOADA = [&](int t, f32x4& x0, f32x4& x1, f32x4& x2, f32x4& x3) {
    const f32x4* p = (const f32x4*)(abase + (size_t)t * 64);
    x0 = __builtin_nontemporal_load(p);
    x1 = __builtin_nontemporal_load(p + 1);
    const f32x4* q = (const f32x4*)(abase + (size_t)t * 64 + 32);
    x2 = __builtin_nontemporal_load(q);
    x3 = __builtin_nontemporal_load(q + 1);
  };

  // prologue: issue tile 0 (6 VMEM ops); iter 0's vmcnt(6) waits for them
  STAGE(0, 0);
  f32x4 c0, c1, c2, c3;
  LOADA(0, c0, c1, c2, c3);

  for (int t = 0; t < 256; ++t) {
    const int buf = t & 1;
    f32x4 n0, n1, n2, n3;
    if (t + 1 < 256) {
      STAGE(buf ^ 1, t + 1);        // 2 global_load_lds, stay in flight
      LOADA(t + 1, n0, n1, n2, n3); // 4 reg loads, stay in flight
      asm volatile("s_waitcnt vmcnt(6)" ::: "memory");  // prev iter's 6 done
    } else {
      n0 = c0; n1 = c1; n2 = c2; n3 = c3;
      asm volatile("s_waitcnt vmcnt(0)" ::: "memory");  // final tile: drain
    }
    __builtin_amdgcn_s_barrier();   // B(t) visible to all waves

    const i64 a0 = pk8(c0, c1, ASCALE);       // k0..k0+31  (x2^14)
    const i64 a1 = pk8(c2, c3, ASCALE);       // k0+32..k0+63
#pragma unroll
    for (int f = 0; f < 8; ++f) {
      const int jrow = f * 16 + l15;
      const i64 b0 = *(const i64*)&Bs[buf][g * 1024 + jrow * 8];
      acc[f] = __builtin_amdgcn_mfma_f32_16x16x32_fp8_fp8(a0, b0, acc[f], 0, 0, 0);
      const i64 b1 = *(const i64*)&Bs[buf][(4 + g) * 1024 + jrow * 8];
      acc[f] = __builtin_amdgcn_mfma_f32_16x16x32_fp8_fp8(a1, b1, acc[f], 0, 0, 0);
    }
    __builtin_amdgcn_s_barrier();   // all waves done reading buf before rewrite
    c0 = n0; c1 = n1; c2 = n2; c3 = n3;
  }

  // epilogue: out = rb*2^-14 + (ra + bias).  C/D: col=lane&15, row=(lane>>4)*4+q
  const float* rabase = ws_ra + (size_t)(r0 + w * 16) * DD;
  float*       obase  = out   + (size_t)(r0 + w * 16) * DD;
#pragma unroll
  for (int f = 0; f < 8; ++f) {
    const int col = f * 16 + l15;
#pragma unroll
    for (int q = 0; q < 4; ++q) {
      const int row = g * 4 + q;
      obase[row * DD + col] = acc[f][q] * INV_ASCALE + rabase[row * DD + col];
    }
  }
}

extern "C" void kernel_launch(void* const* d_in, const int* in_sizes, int n_in,
                              void* d_out, int out_size, void* d_ws, size_t ws_size,
                              hipStream_t stream) {
  const float* h    = (const float*)d_in[0];
  const float* adj  = (const float*)d_in[1];
  const int*   ridx = (const int*)d_in[2];
  const float* W    = (const float*)d_in[3];
  const float* LW   = (const float*)d_in[4];
  const float* RP   = (const float*)d_in[5];
  const float* bias = (const float*)d_in[6];
  float* out = (float*)d_out;

  float* ws_ra = (float*)d_ws;                                   // 8 MB
  void*  tT8   = (void*)((char*)d_ws + (size_t)NV * DD * 4);     // 2 MB fp8

  hipLaunchKernelGGL(k_small, dim3(NV / 8), dim3(128), 0, stream,
                     h, ridx, W, LW, RP, bias, ws_ra, (i32x2*)tT8);
  hipLaunchKernelGGL(k_big, dim3(NV / 64), dim3(256), 0, stream,
                     adj, (const unsigned char*)tT8, ws_ra, out);
}

// Round 4
// 270.692 us; speedup vs baseline: 1.6463x; 1.2810x over previous
//
#include <hip/hip_runtime.h>
#include <hip/hip_bf16.h>

#define NV 16384
#define DD 128

typedef __attribute__((ext_vector_type(4))) float f32x4;
typedef __attribute__((ext_vector_type(2))) int i32x2;
typedef long long i64;

#define ASCALE 16384.0f
#define INV_ASCALE (1.0f / 16384.0f)

__device__ __forceinline__ i64 pk8(f32x4 a, f32x4 b, float s) {
  int lo = 0, hi = 0;
  lo = __builtin_amdgcn_cvt_pk_fp8_f32(a[0] * s, a[1] * s, lo, false);
  lo = __builtin_amdgcn_cvt_pk_fp8_f32(a[2] * s, a[3] * s, lo, true);
  hi = __builtin_amdgcn_cvt_pk_fp8_f32(b[0] * s, b[1] * s, hi, false);
  hi = __builtin_amdgcn_cvt_pk_fp8_f32(b[2] * s, b[3] * s, hi, true);
  i32x2 r; r[0] = lo; r[1] = hi;
  return __builtin_bit_cast(i64, r);
}

// ---------------------------------------------------------------------------
// Kernel 1: rwh = h * reg_param[region_index];  ws_ra = rwh@W + bias (f32);
//           tT8 = (rwh@LW) as fp8 e4m3, k-chunk-major blocked layout:
//           [t=NV/64][g8=8][j=128] x 8 bytes
// ---------------------------------------------------------------------------
__global__ __launch_bounds__(128) void k_small(
    const float* __restrict__ h, const int* __restrict__ ridx,
    const float* __restrict__ W, const float* __restrict__ LW,
    const float* __restrict__ RP, const float* __restrict__ bias,
    float* __restrict__ ws_ra, i32x2* __restrict__ tT8)
{
  __shared__ float rwhs[8][DD];
  const int v0 = blockIdx.x * 8;
  const int j  = threadIdx.x;
#pragma unroll
  for (int v = 0; v < 8; ++v) {
    const int i = v0 + v;
    const int r = ridx[i] & 63;
    rwhs[v][j] = h[(size_t)i * DD + j] * RP[r * DD + j];
  }
  __syncthreads();

  float ra[8], tt[8];
  const float bj = bias[j];
#pragma unroll
  for (int v = 0; v < 8; ++v) { ra[v] = bj; tt[v] = 0.f; }

  for (int d = 0; d < DD; d += 4) {
    f32x4 rv[8];
#pragma unroll
    for (int v = 0; v < 8; ++v) rv[v] = *(const f32x4*)&rwhs[v][d];
#pragma unroll
    for (int dd = 0; dd < 4; ++dd) {
      const float w_  = W[(d + dd) * DD + j];
      const float lw_ = LW[(d + dd) * DD + j];
#pragma unroll
      for (int v = 0; v < 8; ++v) {
        ra[v] = fmaf(rv[v][dd], w_,  ra[v]);
        tt[v] = fmaf(rv[v][dd], lw_, tt[v]);
      }
    }
  }
#pragma unroll
  for (int v = 0; v < 8; ++v) ws_ra[(size_t)(v0 + v) * DD + j] = ra[v];

  int lo = 0, hi = 0;
  lo = __builtin_amdgcn_cvt_pk_fp8_f32(tt[0], tt[1], lo, false);
  lo = __builtin_amdgcn_cvt_pk_fp8_f32(tt[2], tt[3], lo, true);
  hi = __builtin_amdgcn_cvt_pk_fp8_f32(tt[4], tt[5], hi, false);
  hi = __builtin_amdgcn_cvt_pk_fp8_f32(tt[6], tt[7], hi, true);
  i32x2 val; val[0] = lo; val[1] = hi;
  tT8[(v0 >> 6) * 1024 + ((v0 >> 3) & 7) * 128 + j] = val;
}

// ---------------------------------------------------------------------------
// Kernel 2: partial rb = adj[rows, khalf] @ t[khalf].  BM=64, BK=64, fp8.
// Split-K x2 (512 blocks = 2 blocks/CU = 2 waves/SIMD) + depth-3 prefetch
// (4 LDS buffers, counted vmcnt(12), one barrier per iter).  NT=128 iters.
// ---------------------------------------------------------------------------
__global__ __launch_bounds__(256) void k_big(
    const float* __restrict__ adj, const unsigned char* __restrict__ tTb,
    float* __restrict__ part)
{
  __shared__ unsigned char Bs[4][8192] __attribute__((aligned(16)));
  const int tid  = threadIdx.x;
  const int w    = tid >> 6;
  const int lane = tid & 63;
  const int g    = lane >> 4;
  const int l15  = lane & 15;
  const int bid  = blockIdx.x;
  const int mblk = bid >> 1;
  const int kh   = bid & 1;
  const int r0   = mblk * 64;
  const int arow = r0 + w * 16 + l15;
  const float* abase = adj + (size_t)arow * NV + kh * (NV / 2) + g * 8;
  const unsigned char* bbase = tTb + (size_t)kh * 128 * 8192;

  f32x4 acc[8];
#pragma unroll
  for (int f = 0; f < 8; ++f) acc[f] = (f32x4){0.f, 0.f, 0.f, 0.f};

#define STAGE(bufidx, t) do {                                                  \
    _Pragma("unroll")                                                          \
    for (int i_ = 0; i_ < 2; ++i_) {                                           \
      const int unit_ = i_ * 4 + w;                                            \
      const unsigned char* src_ = bbase + (size_t)(t) * 8192 + unit_ * 1024 +  \
                                  lane * 16;                                   \
      __builtin_amdgcn_global_load_lds(                                        \
          (const __attribute__((address_space(1))) unsigned int*)src_,         \
          (__attribute__((address_space(3))) unsigned int*)&Bs[bufidx][unit_ * 1024], \
          16, 0, 0);                                                           \
    } } while (0)

#define LOADA(t, x0, x1, x2, x3) do {                                          \
    const f32x4* p_ = (const f32x4*)(abase + (size_t)(t) * 64);                \
    x0 = __builtin_nontemporal_load(p_);                                       \
    x1 = __builtin_nontemporal_load(p_ + 1);                                   \
    const f32x4* q_ = (const f32x4*)(abase + (size_t)(t) * 64 + 32);           \
    x2 = __builtin_nontemporal_load(q_);                                       \
    x3 = __builtin_nontemporal_load(q_ + 1);                                   \
  } while (0)

#define COMP(bufidx, c0, c1, c2, c3) do {                                      \
    const i64 a0_ = pk8(c0, c1, ASCALE);                                       \
    const i64 a1_ = pk8(c2, c3, ASCALE);                                       \
    _Pragma("unroll")                                                          \
    for (int f_ = 0; f_ < 8; ++f_) {                                           \
      const int jr_ = f_ * 16 + l15;                                           \
      const i64 b0_ = *(const i64*)&Bs[bufidx][g * 1024 + jr_ * 8];            \
      acc[f_] = __builtin_amdgcn_mfma_f32_16x16x32_fp8_fp8(a0_, b0_, acc[f_], 0, 0, 0); \
      const i64 b1_ = *(const i64*)&Bs[bufidx][(4 + g) * 1024 + jr_ * 8];      \
      acc[f_] = __builtin_amdgcn_mfma_f32_16x16x32_fp8_fp8(a1_, b1_, acc[f_], 0, 0, 0); \
    } } while (0)

#define VW12 asm volatile("s_waitcnt vmcnt(12)" ::: "memory")
#define VW6  asm volatile("s_waitcnt vmcnt(6)"  ::: "memory")
#define VW0  asm volatile("s_waitcnt vmcnt(0)"  ::: "memory")
#define BAR  __builtin_amdgcn_s_barrier()

  f32x4 p00, p01, p02, p03, p10, p11, p12, p13;
  f32x4 p20, p21, p22, p23, p30, p31, p32, p33;

  // prologue: tiles 0,1,2 in flight (tile-contiguous issue order: 6 ops each)
  STAGE(0, 0); LOADA(0, p00, p01, p02, p03);
  STAGE(1, 1); LOADA(1, p10, p11, p12, p13);
  STAGE(2, 2); LOADA(2, p20, p21, p22, p23);

  for (int tb = 0; tb < 31; ++tb) {
    const int t = tb * 4;
    VW12; BAR; STAGE(3, t + 3); LOADA(t + 3, p30, p31, p32, p33);
    COMP(0, p00, p01, p02, p03);
    VW12; BAR; STAGE(0, t + 4); LOADA(t + 4, p00, p01, p02, p03);
    COMP(1, p10, p11, p12, p13);
    VW12; BAR; STAGE(1, t + 5); LOADA(t + 5, p10, p11, p12, p13);
    COMP(2, p20, p21, p22, p23);
    VW12; BAR; STAGE(2, t + 6); LOADA(t + 6, p20, p21, p22, p23);
    COMP(3, p30, p31, p32, p33);
  }
  // tail: t = 124..127
  VW12; BAR; STAGE(3, 127); LOADA(127, p30, p31, p32, p33);
  COMP(0, p00, p01, p02, p03);
  VW12; BAR; COMP(1, p10, p11, p12, p13);
  VW6;  BAR; COMP(2, p20, p21, p22, p23);
  VW0;  BAR; COMP(3, p30, p31, p32, p33);

  // partial write: part[bid][64][128], row=g*4+q, col=f*16+l15 (C/D layout)
  float* pbase = part + ((size_t)bid * 64 + w * 16) * DD;
#pragma unroll
  for (int f = 0; f < 8; ++f) {
    const int col = f * 16 + l15;
#pragma unroll
    for (int q = 0; q < 4; ++q) {
      const int row = g * 4 + q;
      pbase[row * DD + col] = acc[f][q];
    }
  }
#undef STAGE
#undef LOADA
#undef COMP
#undef VW12
#undef VW6
#undef VW0
#undef BAR
}

// ---------------------------------------------------------------------------
// Kernel 3: out = (part0 + part1) * 2^-14 + ws_ra   (deterministic reduce)
// ---------------------------------------------------------------------------
__global__ __launch_bounds__(256) void k_reduce(
    const float* __restrict__ part, const float* __restrict__ ws_ra,
    float* __restrict__ out)
{
  const size_t e = ((size_t)blockIdx.x * 256 + threadIdx.x) * 4;
  const int    mblk  = (int)(e >> 13);
  const int    local = (int)(e & 8191);
  const f32x4 p0 = *(const f32x4*)&part[(size_t)(2 * mblk)     * 8192 + local];
  const f32x4 p1 = *(const f32x4*)&part[(size_t)(2 * mblk + 1) * 8192 + local];
  const f32x4 ra = *(const f32x4*)&ws_ra[e];
  f32x4 o;
#pragma unroll
  for (int i = 0; i < 4; ++i) o[i] = (p0[i] + p1[i]) * INV_ASCALE + ra[i];
  *(f32x4*)&out[e] = o;
}

extern "C" void kernel_launch(void* const* d_in, const int* in_sizes, int n_in,
                              void* d_out, int out_size, void* d_ws, size_t ws_size,
                              hipStream_t stream) {
  const float* h    = (const float*)d_in[0];
  const float* adj  = (const float*)d_in[1];
  const int*   ridx = (const int*)d_in[2];
  const float* W    = (const float*)d_in[3];
  const float* LW   = (const float*)d_in[4];
  const float* RP   = (const float*)d_in[5];
  const float* bias = (const float*)d_in[6];
  float* out = (float*)d_out;

  float* ws_ra = (float*)d_ws;                                   // 8 MB @ 0
  void*  tT8   = (void*)((char*)d_ws + (size_t)8  * 1024 * 1024); // 2 MB @ 8M
  float* part  = (float*)((char*)d_ws + (size_t)16 * 1024 * 1024); // 16 MB @ 16M

  hipLaunchKernelGGL(k_small, dim3(NV / 8), dim3(128), 0, stream,
                     h, ridx, W, LW, RP, bias, ws_ra, (i32x2*)tT8);
  hipLaunchKernelGGL(k_big, dim3(NV / 64 * 2), dim3(256), 0, stream,
                     adj, (const unsigned char*)tT8, part);
  hipLaunchKernelGGL(k_reduce, dim3((NV * DD / 4) / 256), dim3(256), 0, stream,
                     part, ws_ra, out);
}

// Round 5
// 256.089 us; speedup vs baseline: 1.7402x; 1.0570x over previous
//
#include <hip/hip_runtime.h>
#include <hip/hip_bf16.h>

#define NV 16384
#define DD 128

typedef __attribute__((ext_vector_type(4))) float f32x4;
typedef __attribute__((ext_vector_type(2))) int i32x2;
typedef long long i64;

#define ASCALE 16384.0f
#define INV_ASCALE (1.0f / 16384.0f)

__device__ __forceinline__ i64 pk8(f32x4 a, f32x4 b, float s) {
  int lo = 0, hi = 0;
  lo = __builtin_amdgcn_cvt_pk_fp8_f32(a[0] * s, a[1] * s, lo, false);
  lo = __builtin_amdgcn_cvt_pk_fp8_f32(a[2] * s, a[3] * s, lo, true);
  hi = __builtin_amdgcn_cvt_pk_fp8_f32(b[0] * s, b[1] * s, hi, false);
  hi = __builtin_amdgcn_cvt_pk_fp8_f32(b[2] * s, b[3] * s, hi, true);
  i32x2 r; r[0] = lo; r[1] = hi;
  return __builtin_bit_cast(i64, r);
}

// ---------------------------------------------------------------------------
// Kernel 1: rwh = h * reg_param[region_index];  ws_ra = rwh@W + bias (f32);
//           tT8 = (rwh@LW) as fp8 e4m3, k-chunk-major blocked layout:
//           [t=NV/64][g8=8][j=128] x 8 bytes
// ---------------------------------------------------------------------------
__global__ __launch_bounds__(128) void k_small(
    const float* __restrict__ h, const int* __restrict__ ridx,
    const float* __restrict__ W, const float* __restrict__ LW,
    const float* __restrict__ RP, const float* __restrict__ bias,
    float* __restrict__ ws_ra, i32x2* __restrict__ tT8)
{
  __shared__ float rwhs[8][DD];
  const int v0 = blockIdx.x * 8;
  const int j  = threadIdx.x;
#pragma unroll
  for (int v = 0; v < 8; ++v) {
    const int i = v0 + v;
    const int r = ridx[i] & 63;
    rwhs[v][j] = h[(size_t)i * DD + j] * RP[r * DD + j];
  }
  __syncthreads();

  float ra[8], tt[8];
  const float bj = bias[j];
#pragma unroll
  for (int v = 0; v < 8; ++v) { ra[v] = bj; tt[v] = 0.f; }

  for (int d = 0; d < DD; d += 4) {
    f32x4 rv[8];
#pragma unroll
    for (int v = 0; v < 8; ++v) rv[v] = *(const f32x4*)&rwhs[v][d];
#pragma unroll
    for (int dd = 0; dd < 4; ++dd) {
      const float w_  = W[(d + dd) * DD + j];
      const float lw_ = LW[(d + dd) * DD + j];
#pragma unroll
      for (int v = 0; v < 8; ++v) {
        ra[v] = fmaf(rv[v][dd], w_,  ra[v]);
        tt[v] = fmaf(rv[v][dd], lw_, tt[v]);
      }
    }
  }
#pragma unroll
  for (int v = 0; v < 8; ++v) ws_ra[(size_t)(v0 + v) * DD + j] = ra[v];

  int lo = 0, hi = 0;
  lo = __builtin_amdgcn_cvt_pk_fp8_f32(tt[0], tt[1], lo, false);
  lo = __builtin_amdgcn_cvt_pk_fp8_f32(tt[2], tt[3], lo, true);
  hi = __builtin_amdgcn_cvt_pk_fp8_f32(tt[4], tt[5], hi, false);
  hi = __builtin_amdgcn_cvt_pk_fp8_f32(tt[6], tt[7], hi, true);
  i32x2 val; val[0] = lo; val[1] = hi;
  tT8[(v0 >> 6) * 1024 + ((v0 >> 3) & 7) * 128 + j] = val;
}

// ---------------------------------------------------------------------------
// Kernel 2: partial rb = adj[rows, khalf] @ t[khalf].  BM=64, BK=64, fp8.
// Split-K x2 (512 blocks = 2 blocks/CU = 2 waves/SIMD) + depth-3 prefetch
// (4 LDS buffers, counted vmcnt(12), one barrier per iter).  NT=128 iters.
// A loads CACHED (round-4 nt hint caused ~1.4x overfetch: two instrs share
// each 128B line; no-allocate defeated the merge).
// ---------------------------------------------------------------------------
__global__ __launch_bounds__(256) void k_big(
    const float* __restrict__ adj, const unsigned char* __restrict__ tTb,
    float* __restrict__ part)
{
  __shared__ unsigned char Bs[4][8192] __attribute__((aligned(16)));
  const int tid  = threadIdx.x;
  const int w    = tid >> 6;
  const int lane = tid & 63;
  const int g    = lane >> 4;
  const int l15  = lane & 15;
  const int bid  = blockIdx.x;
  const int mblk = bid >> 1;
  const int kh   = bid & 1;
  const int r0   = mblk * 64;
  const int arow = r0 + w * 16 + l15;
  const float* abase = adj + (size_t)arow * NV + kh * (NV / 2) + g * 8;
  const unsigned char* bbase = tTb + (size_t)kh * 128 * 8192;

  f32x4 acc[8];
#pragma unroll
  for (int f = 0; f < 8; ++f) acc[f] = (f32x4){0.f, 0.f, 0.f, 0.f};

#define STAGE(bufidx, t) do {                                                  \
    _Pragma("unroll")                                                          \
    for (int i_ = 0; i_ < 2; ++i_) {                                           \
      const int unit_ = i_ * 4 + w;                                            \
      const unsigned char* src_ = bbase + (size_t)(t) * 8192 + unit_ * 1024 +  \
                                  lane * 16;                                   \
      __builtin_amdgcn_global_load_lds(                                        \
          (const __attribute__((address_space(1))) unsigned int*)src_,         \
          (__attribute__((address_space(3))) unsigned int*)&Bs[bufidx][unit_ * 1024], \
          16, 0, 0);                                                           \
    } } while (0)

#define LOADA(t, x0, x1, x2, x3) do {                                          \
    const f32x4* p_ = (const f32x4*)(abase + (size_t)(t) * 64);                \
    x0 = p_[0];                                                                \
    x1 = p_[1];                                                                \
    const f32x4* q_ = (const f32x4*)(abase + (size_t)(t) * 64 + 32);           \
    x2 = q_[0];                                                                \
    x3 = q_[1];                                                                \
  } while (0)

#define COMP(bufidx, c0, c1, c2, c3) do {                                      \
    const i64 a0_ = pk8(c0, c1, ASCALE);                                       \
    const i64 a1_ = pk8(c2, c3, ASCALE);                                       \
    _Pragma("unroll")                                                          \
    for (int f_ = 0; f_ < 8; ++f_) {                                           \
      const int jr_ = f_ * 16 + l15;                                           \
      const i64 b0_ = *(const i64*)&Bs[bufidx][g * 1024 + jr_ * 8];            \
      acc[f_] = __builtin_amdgcn_mfma_f32_16x16x32_fp8_fp8(a0_, b0_, acc[f_], 0, 0, 0); \
      const i64 b1_ = *(const i64*)&Bs[bufidx][(4 + g) * 1024 + jr_ * 8];      \
      acc[f_] = __builtin_amdgcn_mfma_f32_16x16x32_fp8_fp8(a1_, b1_, acc[f_], 0, 0, 0); \
    } } while (0)

#define VW12 asm volatile("s_waitcnt vmcnt(12)" ::: "memory")
#define VW6  asm volatile("s_waitcnt vmcnt(6)"  ::: "memory")
#define VW0  asm volatile("s_waitcnt vmcnt(0)"  ::: "memory")
#define BAR  __builtin_amdgcn_s_barrier()

  f32x4 p00, p01, p02, p03, p10, p11, p12, p13;
  f32x4 p20, p21, p22, p23, p30, p31, p32, p33;

  // prologue: tiles 0,1,2 in flight (tile-contiguous issue order: 6 ops each)
  STAGE(0, 0); LOADA(0, p00, p01, p02, p03);
  STAGE(1, 1); LOADA(1, p10, p11, p12, p13);
  STAGE(2, 2); LOADA(2, p20, p21, p22, p23);

  for (int tb = 0; tb < 31; ++tb) {
    const int t = tb * 4;
    VW12; BAR; STAGE(3, t + 3); LOADA(t + 3, p30, p31, p32, p33);
    COMP(0, p00, p01, p02, p03);
    VW12; BAR; STAGE(0, t + 4); LOADA(t + 4, p00, p01, p02, p03);
    COMP(1, p10, p11, p12, p13);
    VW12; BAR; STAGE(1, t + 5); LOADA(t + 5, p10, p11, p12, p13);
    COMP(2, p20, p21, p22, p23);
    VW12; BAR; STAGE(2, t + 6); LOADA(t + 6, p20, p21, p22, p23);
    COMP(3, p30, p31, p32, p33);
  }
  // tail: t = 124..127
  VW12; BAR; STAGE(3, 127); LOADA(127, p30, p31, p32, p33);
  COMP(0, p00, p01, p02, p03);
  VW12; BAR; COMP(1, p10, p11, p12, p13);
  VW6;  BAR; COMP(2, p20, p21, p22, p23);
  VW0;  BAR; COMP(3, p30, p31, p32, p33);

  // partial write: part[bid][64][128], row=g*4+q, col=f*16+l15 (C/D layout)
  float* pbase = part + ((size_t)bid * 64 + w * 16) * DD;
#pragma unroll
  for (int f = 0; f < 8; ++f) {
    const int col = f * 16 + l15;
#pragma unroll
    for (int q = 0; q < 4; ++q) {
      const int row = g * 4 + q;
      pbase[row * DD + col] = acc[f][q];
    }
  }
#undef STAGE
#undef LOADA
#undef COMP
#undef VW12
#undef VW6
#undef VW0
#undef BAR
}

// ---------------------------------------------------------------------------
// Kernel 3: out = (part0 + part1) * 2^-14 + ws_ra   (deterministic reduce)
// ---------------------------------------------------------------------------
__global__ __launch_bounds__(256) void k_reduce(
    const float* __restrict__ part, const float* __restrict__ ws_ra,
    float* __restrict__ out)
{
  const size_t e = ((size_t)blockIdx.x * 256 + threadIdx.x) * 4;
  const int    mblk  = (int)(e >> 13);
  const int    local = (int)(e & 8191);
  const f32x4 p0 = *(const f32x4*)&part[(size_t)(2 * mblk)     * 8192 + local];
  const f32x4 p1 = *(const f32x4*)&part[(size_t)(2 * mblk + 1) * 8192 + local];
  const f32x4 ra = *(const f32x4*)&ws_ra[e];
  f32x4 o;
#pragma unroll
  for (int i = 0; i < 4; ++i) o[i] = (p0[i] + p1[i]) * INV_ASCALE + ra[i];
  *(f32x4*)&out[e] = o;
}

extern "C" void kernel_launch(void* const* d_in, const int* in_sizes, int n_in,
                              void* d_out, int out_size, void* d_ws, size_t ws_size,
                              hipStream_t stream) {
  const float* h    = (const float*)d_in[0];
  const float* adj  = (const float*)d_in[1];
  const int*   ridx = (const int*)d_in[2];
  const float* W    = (const float*)d_in[3];
  const float* LW   = (const float*)d_in[4];
  const float* RP   = (const float*)d_in[5];
  const float* bias = (const float*)d_in[6];
  float* out = (float*)d_out;

  float* ws_ra = (float*)d_ws;                                   // 8 MB @ 0
  void*  tT8   = (void*)((char*)d_ws + (size_t)8  * 1024 * 1024); // 2 MB @ 8M
  float* part  = (float*)((char*)d_ws + (size_t)16 * 1024 * 1024); // 16 MB @ 16M

  hipLaunchKernelGGL(k_small, dim3(NV / 8), dim3(128), 0, stream,
                     h, ridx, W, LW, RP, bias, ws_ra, (i32x2*)tT8);
  hipLaunchKernelGGL(k_big, dim3(NV / 64 * 2), dim3(256), 0, stream,
                     adj, (const unsigned char*)tT8, part);
  hipLaunchKernelGGL(k_reduce, dim3((NV * DD / 4) / 256), dim3(256), 0, stream,
                     part, ws_ra, out);
}